// Round 2
// baseline (59.286 us; speedup 1.0000x reference)
//
#include <hip/hip_runtime.h>

typedef __attribute__((ext_vector_type(8))) short short8;
typedef __attribute__((ext_vector_type(4))) float f32x4;
typedef unsigned int uint32;
typedef unsigned short ushort_t;

// LDS layout (bytes). All bf16, row-major, XOR-swizzled. Total 48 KB.
#define LDS_FB   0u        // Fb  [128][64]  stride 128B, swz mask 7
#define LDS_FBT  16384u    // FbT [64][128]  stride 256B, swz mask 15
#define LDS_GHT  32768u    // G, then HT (in-place) [64][64] stride 128B, mask 7
#define LDS_KB   40960u    // Kw row-major [64][64] stride 128B, mask 7

__device__ __forceinline__ uint32 swz(uint32 base, uint32 row, uint32 colByte,
                                      uint32 stride, uint32 mask) {
    return (base + row * stride + colByte) ^ ((row & mask) << 4);
}
__device__ __forceinline__ ushort_t f2bf(float x) {  // RNE f32 -> bf16 bits
    uint32 u = __float_as_uint(x);
    return (ushort_t)((u + 0x7FFFu + ((u >> 16) & 1u)) >> 16);
}
__device__ __forceinline__ float bf2f(ushort_t b) {
    return __uint_as_float(((uint32)b) << 16);
}

__global__ __launch_bounds__(256, 3)
void sam3e_kernel(const float* __restrict__ F,
                  const float* __restrict__ Kw,
                  const float* __restrict__ Qw,
                  float* __restrict__ out) {
    __shared__ __align__(128) unsigned char smem[49152];
    const int t    = threadIdx.x;
    const int lane = t & 63;
    const int wave = t >> 6;          // 0..3
    const int b    = blockIdx.x;
    const int r16  = lane & 15;
    const int kq   = lane >> 4;       // 0..3

    // ---- stage F (batch b): Fb row-major + FbT transposed (pair-packed)
    const float* Fg = F + (size_t)b * 8192;
    {
        int p  = t >> 4;              // 0..15
        int c4 = (t & 15) * 4;        // float column
        #pragma unroll
        for (int i = 0; i < 4; ++i) {
            int n = 2 * p + 32 * i;   // even row; thread owns rows n, n+1
            float4 va = *(const float4*)(Fg + n * 64 + c4);
            float4 vb = *(const float4*)(Fg + (n + 1) * 64 + c4);
            ushort_t a0 = f2bf(va.x), a1 = f2bf(va.y), a2 = f2bf(va.z), a3 = f2bf(va.w);
            ushort_t b0 = f2bf(vb.x), b1 = f2bf(vb.y), b2 = f2bf(vb.z), b3 = f2bf(vb.w);
            uint2 pa, pb;
            pa.x = (uint32)a0 | ((uint32)a1 << 16); pa.y = (uint32)a2 | ((uint32)a3 << 16);
            pb.x = (uint32)b0 | ((uint32)b1 << 16); pb.y = (uint32)b2 | ((uint32)b3 << 16);
            *(uint2*)(smem + swz(LDS_FB, n,     2u * c4, 128u, 7u)) = pa;
            *(uint2*)(smem + swz(LDS_FB, n + 1, 2u * c4, 128u, 7u)) = pb;
            uint32 t0 = (uint32)a0 | ((uint32)b0 << 16);
            uint32 t1 = (uint32)a1 | ((uint32)b1 << 16);
            uint32 t2 = (uint32)a2 | ((uint32)b2 << 16);
            uint32 t3 = (uint32)a3 | ((uint32)b3 << 16);
            *(uint32*)(smem + swz(LDS_FBT, c4 + 0, 2u * n, 256u, 15u)) = t0;
            *(uint32*)(smem + swz(LDS_FBT, c4 + 1, 2u * n, 256u, 15u)) = t1;
            *(uint32*)(smem + swz(LDS_FBT, c4 + 2, 2u * n, 256u, 15u)) = t2;
            *(uint32*)(smem + swz(LDS_FBT, c4 + 3, 2u * n, 256u, 15u)) = t3;
        }
    }

    // ---- stage K_w -> bf16 LDS (4096 floats, float4-vectorized)
    #pragma unroll
    for (int i = 0; i < 4; ++i) {
        int idx4 = t + 256 * i;       // float4 index
        int r = idx4 >> 4;
        int c = (idx4 & 15) * 4;
        float4 v = *(const float4*)(Kw + 4 * idx4);
        uint2 pk;
        pk.x = (uint32)f2bf(v.x) | ((uint32)f2bf(v.y) << 16);
        pk.y = (uint32)f2bf(v.z) | ((uint32)f2bf(v.w) << 16);
        *(uint2*)(smem + swz(LDS_KB, r, 2u * c, 128u, 7u)) = pk;
    }

    // ---- Q_w B-fragments -> registers (no LDS). qf[kk][tn], lane holds
    // Qw[e][d0..d0+8) with e = 16*tn + r16, d0 = 32*kk + 8*kq.
    short8 qf[2][4];
    #pragma unroll
    for (int kk = 0; kk < 2; ++kk) {
        #pragma unroll
        for (int tn = 0; tn < 4; ++tn) {
            const float* qp = Qw + (16 * tn + r16) * 64 + 32 * kk + 8 * kq;
            float4 u0 = *(const float4*)(qp);
            float4 u1 = *(const float4*)(qp + 4);
            short8 q;
            q[0] = (short)f2bf(u0.x); q[1] = (short)f2bf(u0.y);
            q[2] = (short)f2bf(u0.z); q[3] = (short)f2bf(u0.w);
            q[4] = (short)f2bf(u1.x); q[5] = (short)f2bf(u1.y);
            q[6] = (short)f2bf(u1.z); q[7] = (short)f2bf(u1.w);
            qf[kk][tn] = q;
        }
    }
    __syncthreads();

    // ---- G = F^T F  (64x64, K=128). Wave w owns row band [16w,16w+16).
    f32x4 accG[4];
    #pragma unroll
    for (int i = 0; i < 4; ++i) accG[i] = (f32x4){0.f, 0.f, 0.f, 0.f};
    #pragma unroll
    for (int kk = 0; kk < 4; ++kk) {
        uint32 kb = (uint32)(32 * kk + 8 * kq) * 2u;
        short8 a = *(const short8*)(smem + swz(LDS_FBT, 16 * wave + r16, kb, 256u, 15u));
        #pragma unroll
        for (int tn = 0; tn < 4; ++tn) {
            short8 bb = *(const short8*)(smem + swz(LDS_FBT, 16 * tn + r16, kb, 256u, 15u));
            accG[tn] = __builtin_amdgcn_mfma_f32_16x16x32_bf16(a, bb, accG[tn], 0, 0, 0);
        }
    }
    // write G band w (wave-local rows; read back only by this wave)
    #pragma unroll
    for (int tn = 0; tn < 4; ++tn)
        #pragma unroll
        for (int r = 0; r < 4; ++r)
            *(ushort_t*)(smem + swz(LDS_GHT, 16 * wave + 4 * kq + r,
                                    2u * (16 * tn + r16), 128u, 7u)) = f2bf(accG[tn][r]);

    // Wave-local RAW on GHT band w: DS is in-order per wave; pin compiler order.
    asm volatile("s_waitcnt lgkmcnt(0)" ::: "memory");
    __builtin_amdgcn_sched_barrier(0);

    // ---- HT = G @ K_w^T (64x64, K=64), in-place over G (own band only).
    f32x4 accH[4];
    #pragma unroll
    for (int i = 0; i < 4; ++i) accH[i] = (f32x4){0.f, 0.f, 0.f, 0.f};
    #pragma unroll
    for (int kk = 0; kk < 2; ++kk) {
        uint32 kb = (uint32)(32 * kk + 8 * kq) * 2u;
        short8 a = *(const short8*)(smem + swz(LDS_GHT, 16 * wave + r16, kb, 128u, 7u));
        #pragma unroll
        for (int tn = 0; tn < 4; ++tn) {
            short8 bb = *(const short8*)(smem + swz(LDS_KB, 16 * tn + r16, kb, 128u, 7u));
            accH[tn] = __builtin_amdgcn_mfma_f32_16x16x32_bf16(a, bb, accH[tn], 0, 0, 0);
        }
    }
    __builtin_amdgcn_sched_barrier(0);   // keep HT writes after all G reads above
    #pragma unroll
    for (int tn = 0; tn < 4; ++tn)
        #pragma unroll
        for (int r = 0; r < 4; ++r)
            *(ushort_t*)(smem + swz(LDS_GHT, 16 * wave + 4 * kq + r,
                                    2u * (16 * tn + r16), 128u, 7u)) = f2bf(accH[tn][r]);
    __syncthreads();

    // ---- T = F @ H (B = HT rows), QF = F @ Q_w^T (B = qf regs). 128x64, K=64.
    f32x4 accT[2][4], accQ[2][4];
    #pragma unroll
    for (int i = 0; i < 2; ++i)
        #pragma unroll
        for (int j = 0; j < 4; ++j) {
            accT[i][j] = (f32x4){0.f, 0.f, 0.f, 0.f};
            accQ[i][j] = (f32x4){0.f, 0.f, 0.f, 0.f};
        }
    #pragma unroll
    for (int kk = 0; kk < 2; ++kk) {
        uint32 kb = (uint32)(32 * kk + 8 * kq) * 2u;
        short8 a0 = *(const short8*)(smem + swz(LDS_FB, 16 * (2 * wave + 0) + r16, kb, 128u, 7u));
        short8 a1 = *(const short8*)(smem + swz(LDS_FB, 16 * (2 * wave + 1) + r16, kb, 128u, 7u));
        #pragma unroll
        for (int tn = 0; tn < 4; ++tn) {
            short8 bt = *(const short8*)(smem + swz(LDS_GHT, 16 * tn + r16, kb, 128u, 7u));
            accT[0][tn] = __builtin_amdgcn_mfma_f32_16x16x32_bf16(a0, bt, accT[0][tn], 0, 0, 0);
            accQ[0][tn] = __builtin_amdgcn_mfma_f32_16x16x32_bf16(a0, qf[kk][tn], accQ[0][tn], 0, 0, 0);
            accT[1][tn] = __builtin_amdgcn_mfma_f32_16x16x32_bf16(a1, bt, accT[1][tn], 0, 0, 0);
            accQ[1][tn] = __builtin_amdgcn_mfma_f32_16x16x32_bf16(a1, qf[kk][tn], accQ[1][tn], 0, 0, 0);
        }
    }

    // ---- epilogue: out = F .* T + QF
    float* og = out + (size_t)b * 8192;
    #pragma unroll
    for (int i2 = 0; i2 < 2; ++i2) {
        #pragma unroll
        for (int tn = 0; tn < 4; ++tn) {
            #pragma unroll
            for (int r = 0; r < 4; ++r) {
                int n = 16 * (2 * wave + i2) + 4 * kq + r;
                int d = 16 * tn + r16;
                float f = bf2f(*(const ushort_t*)(smem + swz(LDS_FB, n, 2u * d, 128u, 7u)));
                og[n * 64 + d] = fmaf(f, accT[i2][tn][r], accQ[i2][tn][r]);
            }
        }
    }
}

extern "C" void kernel_launch(void* const* d_in, const int* in_sizes, int n_in,
                              void* d_out, int out_size, void* d_ws, size_t ws_size,
                              hipStream_t stream) {
    const float* F  = (const float*)d_in[0];
    const float* Kw = (const float*)d_in[1];
    const float* Qw = (const float*)d_in[2];
    float* out = (float*)d_out;
    int Bt = in_sizes[0] / (128 * 64);   // 4096
    sam3e_kernel<<<dim3(Bt), dim3(256), 0, stream>>>(F, Kw, Qw, out);
}

// Round 4
// 45.845 us; speedup vs baseline: 1.2932x; 1.2932x over previous
//
#include <hip/hip_runtime.h>

typedef __attribute__((ext_vector_type(8))) short short8;
typedef __attribute__((ext_vector_type(4))) short short4v;
typedef __attribute__((ext_vector_type(4))) float f32x4;
typedef unsigned int uint32;
typedef unsigned short ushort_t;

// LDS layout (bytes). All bf16 tiles, 128B row stride, XOR-swizzled. 40 KB.
#define LDS_FB   0u        // F   [128][64]
#define LDS_GHT  16384u    // G, then HT in-place [64][64]
#define LDS_KB   24576u    // Kw  [64][64] (row-major)
#define LDS_QB   32768u    // Qw  [64][64] (row-major)

__device__ __forceinline__ uint32 swz(uint32 base, uint32 row, uint32 colByte) {
    return (base + row * 128u + colByte) ^ ((row & 7u) << 4);
}
__device__ __forceinline__ uint32 pk2(float lo, float hi) {   // v_cvt_pk_bf16_f32 (RNE)
    uint32 r;
    asm("v_cvt_pk_bf16_f32 %0, %1, %2" : "=v"(r) : "v"(lo), "v"(hi));
    return r;
}
__device__ __forceinline__ ushort_t bfbits(float x) {         // RNE f32 -> bf16 bits
    uint32 u = __float_as_uint(x);
    return (ushort_t)((u + 0x7FFFu + ((u >> 16) & 1u)) >> 16);
}
__device__ __forceinline__ float bf2f(ushort_t b) {
    return __uint_as_float(((uint32)b) << 16);
}
__device__ __forceinline__ short4v tr16(uint32 addr) {        // ds_read_b64_tr_b16
    short4v d;
    asm volatile("ds_read_b64_tr_b16 %0, %1" : "=v"(d) : "v"(addr));
    return d;
}
#define CAT8(lo, hi) __builtin_shufflevector(lo, hi, 0, 1, 2, 3, 4, 5, 6, 7)

__global__ __launch_bounds__(256, 4)
void sam3e_kernel(const float* __restrict__ F,
                  const float* __restrict__ Kw,
                  const float* __restrict__ Qw,
                  float* __restrict__ out) {
    __shared__ __align__(128) unsigned char smem[40960];
    const uint32 ldsb = (uint32)(size_t)(void*)smem;
    const int t    = threadIdx.x;
    const int lane = t & 63;
    const int wave = t >> 6;          // 0..3
    const int b    = blockIdx.x;
    const uint32 r16 = (uint32)(lane & 15);
    const uint32 kq  = (uint32)(lane >> 4);   // 0..3

    // ---- stage F (batch b) -> bf16 LDS, row-major only (HW cvt_pk)
    const float* Fg = F + (size_t)b * 8192;
    {
        int n0 = t >> 4;
        int c4 = (t & 15) * 4;
        #pragma unroll
        for (int i = 0; i < 8; ++i) {
            int n = n0 + 16 * i;
            float4 v = *(const float4*)(Fg + n * 64 + c4);
            uint2 pk; pk.x = pk2(v.x, v.y); pk.y = pk2(v.z, v.w);
            *(uint2*)(smem + swz(LDS_FB, (uint32)n, (uint32)(2 * c4))) = pk;
        }
    }
    // ---- stage Kw, Qw (each 1024 float4s across 256 threads)
    #pragma unroll
    for (int i = 0; i < 4; ++i) {
        int idx4 = t + 256 * i;
        uint32 r = (uint32)(idx4 >> 4);
        uint32 cB = (uint32)((idx4 & 15) * 8);
        float4 vk = *(const float4*)(Kw + 4 * idx4);
        float4 vq = *(const float4*)(Qw + 4 * idx4);
        uint2 pk; pk.x = pk2(vk.x, vk.y); pk.y = pk2(vk.z, vk.w);
        uint2 pq; pq.x = pk2(vq.x, vq.y); pq.y = pk2(vq.z, vq.w);
        *(uint2*)(smem + swz(LDS_KB, r, cB)) = pk;
        *(uint2*)(smem + swz(LDS_QB, r, cB)) = pq;
    }
    __syncthreads();

    // ---- G = F^T F (64x64, K=128). Fragments via hardware transpose-reads.
    // Group kq covers rows 8kq..8kq+8 of each 32-row k-chunk; lane gets col r16.
    f32x4 accG[4];
    #pragma unroll
    for (int i = 0; i < 4; ++i) accG[i] = (f32x4){0.f, 0.f, 0.f, 0.f};
    const uint32 trc = 8u * (r16 & 3u);   // byte-in-16col-tile
    const uint32 trr = r16 >> 2;          // row-in-4row-block
    #pragma unroll
    for (int kk = 0; kk < 4; ++kk) {
        uint32 rA = (uint32)(32 * kk) + 8u * kq + trr;
        short4v alo = tr16(ldsb + swz(LDS_FB, rA,      32u * (uint32)wave + trc));
        short4v ahi = tr16(ldsb + swz(LDS_FB, rA + 4u, 32u * (uint32)wave + trc));
        short4v blo[4], bhi[4];
        #pragma unroll
        for (int tn = 0; tn < 4; ++tn) {
            blo[tn] = tr16(ldsb + swz(LDS_FB, rA,      32u * (uint32)tn + trc));
            bhi[tn] = tr16(ldsb + swz(LDS_FB, rA + 4u, 32u * (uint32)tn + trc));
        }
        asm volatile("s_waitcnt lgkmcnt(0)" ::: "memory");
        __builtin_amdgcn_sched_barrier(0);
        short8 a = CAT8(alo, ahi);
        #pragma unroll
        for (int tn = 0; tn < 4; ++tn) {
            short8 bb = CAT8(blo[tn], bhi[tn]);
            accG[tn] = __builtin_amdgcn_mfma_f32_16x16x32_bf16(a, bb, accG[tn], 0, 0, 0);
        }
    }
    // write G band w (wave-local rows: only this wave reads them back)
    #pragma unroll
    for (int tn = 0; tn < 4; ++tn)
        #pragma unroll
        for (int r = 0; r < 4; ++r)
            *(ushort_t*)(smem + swz(LDS_GHT, 16u * (uint32)wave + 4u * kq + (uint32)r,
                                    32u * (uint32)tn + 2u * r16)) = bfbits(accG[tn][r]);
    asm volatile("s_waitcnt lgkmcnt(0)" ::: "memory");  // order G-write -> G-read (same wave)

    // ---- HT = G @ Kw^T (64x64, K=64), band w in-place over G band w.
    f32x4 accH[4];
    #pragma unroll
    for (int i = 0; i < 4; ++i) accH[i] = (f32x4){0.f, 0.f, 0.f, 0.f};
    #pragma unroll
    for (int kk = 0; kk < 2; ++kk) {
        uint32 cb = 64u * (uint32)kk + 16u * kq;
        short8 a = *(const short8*)(smem + swz(LDS_GHT, 16u * (uint32)wave + r16, cb));
        #pragma unroll
        for (int tn = 0; tn < 4; ++tn) {
            short8 bb = *(const short8*)(smem + swz(LDS_KB, 16u * (uint32)tn + r16, cb));
            accH[tn] = __builtin_amdgcn_mfma_f32_16x16x32_bf16(a, bb, accH[tn], 0, 0, 0);
        }
    }
    asm volatile("" ::: "memory");  // keep HT stores below G reads (compiler fence)
    #pragma unroll
    for (int tn = 0; tn < 4; ++tn)
        #pragma unroll
        for (int r = 0; r < 4; ++r)
            *(ushort_t*)(smem + swz(LDS_GHT, 16u * (uint32)wave + 4u * kq + (uint32)r,
                                    32u * (uint32)tn + 2u * r16)) = bfbits(accH[tn][r]);
    __syncthreads();

    // ---- T = F @ H (B from HT rows), QF = F @ Qw^T (B from QB rows). 128x64, K=64.
    f32x4 accT[2][4], accQ[2][4];
    #pragma unroll
    for (int i = 0; i < 2; ++i)
        #pragma unroll
        for (int j = 0; j < 4; ++j) {
            accT[i][j] = (f32x4){0.f, 0.f, 0.f, 0.f};
            accQ[i][j] = (f32x4){0.f, 0.f, 0.f, 0.f};
        }
    #pragma unroll
    for (int kk = 0; kk < 2; ++kk) {
        uint32 cb = 64u * (uint32)kk + 16u * kq;
        short8 a0 = *(const short8*)(smem + swz(LDS_FB, 16u * (uint32)(2 * wave + 0) + r16, cb));
        short8 a1 = *(const short8*)(smem + swz(LDS_FB, 16u * (uint32)(2 * wave + 1) + r16, cb));
        #pragma unroll
        for (int tn = 0; tn < 4; ++tn) {
            short8 bt = *(const short8*)(smem + swz(LDS_GHT, 16u * (uint32)tn + r16, cb));
            short8 bq = *(const short8*)(smem + swz(LDS_QB,  16u * (uint32)tn + r16, cb));
            accT[0][tn] = __builtin_amdgcn_mfma_f32_16x16x32_bf16(a0, bt, accT[0][tn], 0, 0, 0);
            accQ[0][tn] = __builtin_amdgcn_mfma_f32_16x16x32_bf16(a0, bq, accQ[0][tn], 0, 0, 0);
            accT[1][tn] = __builtin_amdgcn_mfma_f32_16x16x32_bf16(a1, bt, accT[1][tn], 0, 0, 0);
            accQ[1][tn] = __builtin_amdgcn_mfma_f32_16x16x32_bf16(a1, bq, accQ[1][tn], 0, 0, 0);
        }
    }

    // ---- epilogue: out = F .* T + QF
    float* og = out + (size_t)b * 8192;
    #pragma unroll
    for (int i2 = 0; i2 < 2; ++i2) {
        #pragma unroll
        for (int tn = 0; tn < 4; ++tn) {
            #pragma unroll
            for (int r = 0; r < 4; ++r) {
                uint32 n = 16u * (uint32)(2 * wave + i2) + 4u * kq + (uint32)r;
                uint32 d = 16u * (uint32)tn + r16;
                float f = bf2f(*(const ushort_t*)(smem + swz(LDS_FB, n, 2u * d)));
                og[n * 64 + d] = fmaf(f, accT[i2][tn][r], accQ[i2][tn][r]);
            }
        }
    }
}

extern "C" void kernel_launch(void* const* d_in, const int* in_sizes, int n_in,
                              void* d_out, int out_size, void* d_ws, size_t ws_size,
                              hipStream_t stream) {
    const float* F  = (const float*)d_in[0];
    const float* Kw = (const float*)d_in[1];
    const float* Qw = (const float*)d_in[2];
    float* out = (float*)d_out;
    int Bt = in_sizes[0] / (128 * 64);   // 4096
    sam3e_kernel<<<dim3(Bt), dim3(256), 0, stream>>>(F, Kw, Qw, out);
}